// Round 1
// baseline (1239.438 us; speedup 1.0000x reference)
//
#include <hip/hip_runtime.h>
#include <hip/hip_bf16.h>

#define N_NODES 50000
#define DIM 256
#define N_EDGES 320000
#define BM 32
#define LDA 264   // bf16 elements per LDS row: 256 + 8 pad -> 528B stride, 2-way bank alias (free)

typedef __attribute__((ext_vector_type(8))) short short8;
typedef __attribute__((ext_vector_type(4))) float f32x4;
typedef __attribute__((ext_vector_type(4))) unsigned short ushort4v;

static __device__ __forceinline__ unsigned short f2bf(float f) {
  unsigned int u = __float_as_uint(f);
  return (unsigned short)((u + 0x7FFFu + ((u >> 16) & 1u)) >> 16);  // RNE
}

__global__ __launch_bounds__(256) void k_count(const int* __restrict__ dst,
                                               int* __restrict__ deg) {
  int e = blockIdx.x * 256 + threadIdx.x;
  if (e < N_EDGES) atomicAdd(&deg[dst[e]], 1);
}

__global__ __launch_bounds__(256) void k_dinv(const int* __restrict__ deg,
                                              float* __restrict__ dinv) {
  int i = blockIdx.x * 256 + threadIdx.x;
  if (i < N_NODES) dinv[i] = rsqrtf((float)(deg[i] + 1));  // +1 self-loop; always > 0
}

__global__ __launch_bounds__(256) void k_wconv(const float* __restrict__ W,
                                               unsigned short* __restrict__ wbf) {
  int i = blockIdx.x * 256 + threadIdx.x;  // quad index, 16384 total
  const float4 v = ((const float4*)W)[i];
  ushort4v r;
  r.x = f2bf(v.x); r.y = f2bf(v.y); r.z = f2bf(v.z); r.w = f2bf(v.w);
  *(ushort4v*)(wbf + i * 4) = r;
}

// out[i] = emb[nodes[i]] * dinv[i]^2   (self-loop term; also zero-initializes accumulation)
__global__ __launch_bounds__(256) void k_selfloop(const int* __restrict__ nodes,
                                                  const float* __restrict__ emb,
                                                  const float* __restrict__ dinv,
                                                  float* __restrict__ out) {
  int idx = blockIdx.x * 256 + threadIdx.x;  // float4 index, N*64 total
  int row = idx >> 6;
  if (row >= N_NODES) return;
  int c4 = idx & 63;
  int nr = nodes[row];
  float s = dinv[row];
  s *= s;
  float4 v = ((const float4*)(emb + (size_t)nr * DIM))[c4];
  v.x *= s; v.y *= s; v.z *= s; v.w *= s;
  ((float4*)(out + (size_t)row * DIM))[c4] = v;
}

// One wave per edge (grid-stride): gather emb[nodes[src]] row, scale, atomic-scatter to out[dst].
__global__ __launch_bounds__(256) void k_agg(const int* __restrict__ nodes,
                                             const int* __restrict__ src,
                                             const int* __restrict__ dst,
                                             const float* __restrict__ dinv,
                                             const float* __restrict__ emb,
                                             float* out, int nwaves) {
  int gw = (blockIdx.x * 256 + threadIdx.x) >> 6;
  int lane = threadIdx.x & 63;
  for (int e = gw; e < N_EDGES; e += nwaves) {
    int s = src[e], d = dst[e];
    float nrm = dinv[s] * dinv[d];
    int nr = nodes[s];
    float4 v = ((const float4*)(emb + (size_t)nr * DIM))[lane];
    float* op = out + (size_t)d * DIM + lane * 4;
    unsafeAtomicAdd(op + 0, v.x * nrm);
    unsafeAtomicAdd(op + 1, v.y * nrm);
    unsafeAtomicAdd(op + 2, v.z * nrm);
    unsafeAtomicAdd(op + 3, v.w * nrm);
  }
}

// In-place: out = relu(agg @ W^T + b). BM=32 rows x 256 cols per block, 4 waves.
// Wave w: rows 0..31 x cols [w*64, w*64+64). MFMA 16x16x32 bf16.
// A frag: row = lane&15, k = (lane>>4)*8 + i (contiguous 8 bf16 from LDS).
// B frag: col = lane&15 (= W row), k contiguous -> read W[col][k..k+7] bf16 from global (L2-hot).
// C/D: col = lane&15, row = (lane>>4)*4 + reg   [guide-verified m89/m91]
__global__ __launch_bounds__(256) void k_gemm(const float* agg,
                                              const unsigned short* __restrict__ wbf,
                                              const float* __restrict__ bias,
                                              float* out) {
  __shared__ unsigned short As[BM * LDA];
  const int tid = threadIdx.x;
  const int row0 = blockIdx.x * BM;

  // Stage A tile (32 x 256 fp32 -> bf16). 8 threads per row, 8 float4 each.
  {
    int r = tid >> 3;
    int grow = row0 + r;
    const float4* srcp = (const float4*)(agg + (size_t)grow * DIM);
    unsigned short* lrow = &As[r * LDA];
#pragma unroll
    for (int j = 0; j < 8; ++j) {
      int c4 = (tid & 7) + j * 8;
      float4 v = make_float4(0.f, 0.f, 0.f, 0.f);
      if (grow < N_NODES) v = srcp[c4];
      int c = c4 * 4;
      lrow[c] = f2bf(v.x); lrow[c + 1] = f2bf(v.y);
      lrow[c + 2] = f2bf(v.z); lrow[c + 3] = f2bf(v.w);
    }
  }
  __syncthreads();

  const int wv = tid >> 6, lane = tid & 63;
  const int l15 = lane & 15, kq = lane >> 4;
  const int cb = wv * 64;
  f32x4 acc[2][4] = {};
#pragma unroll
  for (int ks = 0; ks < 8; ++ks) {
    const int kb = ks * 32 + kq * 8;
    short8 a0 = *(const short8*)&As[l15 * LDA + kb];
    short8 a1 = *(const short8*)&As[(16 + l15) * LDA + kb];
    short8 b[4];
#pragma unroll
    for (int f = 0; f < 4; ++f)
      b[f] = *(const short8*)(wbf + (cb + f * 16 + l15) * 256 + kb);
#pragma unroll
    for (int f = 0; f < 4; ++f) {
      acc[0][f] = __builtin_amdgcn_mfma_f32_16x16x32_bf16(a0, b[f], acc[0][f], 0, 0, 0);
      acc[1][f] = __builtin_amdgcn_mfma_f32_16x16x32_bf16(a1, b[f], acc[1][f], 0, 0, 0);
    }
  }
  // Epilogue: + bias, relu, store fp32.
#pragma unroll
  for (int h = 0; h < 2; ++h) {
    int rb = row0 + h * 16 + kq * 4;
#pragma unroll
    for (int f = 0; f < 4; ++f) {
      int col = cb + f * 16 + l15;
      float bv = bias[col];
#pragma unroll
      for (int g = 0; g < 4; ++g) {
        int r = rb + g;
        if (r < N_NODES) {
          float v = acc[h][f][g] + bv;
          out[(size_t)r * DIM + col] = fmaxf(v, 0.f);
        }
      }
    }
  }
}

extern "C" void kernel_launch(void* const* d_in, const int* in_sizes, int n_in,
                              void* d_out, int out_size, void* d_ws, size_t ws_size,
                              hipStream_t stream) {
  const int* nodes = (const int*)d_in[0];
  const int* edges = (const int*)d_in[1];
  const float* emb = (const float*)d_in[2];
  const float* W = (const float*)d_in[3];
  const float* bias = (const float*)d_in[4];
  float* out = (float*)d_out;

  // Workspace layout: deg int[50000] @0, dinv float[50000] @200192, W bf16 @400384 (~531 KB total)
  int* deg = (int*)d_ws;
  float* dinv = (float*)((char*)d_ws + 200192);
  unsigned short* wbf = (unsigned short*)((char*)d_ws + 400384);

  const int* srcp = edges;             // edges[0]
  const int* dstp = edges + N_EDGES;   // edges[1]

  hipMemsetAsync(deg, 0, N_NODES * sizeof(int), stream);
  k_count<<<(N_EDGES + 255) / 256, 256, 0, stream>>>(dstp, deg);
  k_dinv<<<(N_NODES + 255) / 256, 256, 0, stream>>>(deg, dinv);
  k_wconv<<<64, 256, 0, stream>>>(W, wbf);
  k_selfloop<<<12500, 256, 0, stream>>>(nodes, emb, dinv, out);
  const int nblocks = 8192;
  k_agg<<<nblocks, 256, 0, stream>>>(nodes, srcp, dstp, dinv, emb, out, nblocks * 4);
  k_gemm<<<(N_NODES + BM - 1) / BM, 256, 0, stream>>>(out, wbf, bias, out);
}

// Round 2
// 278.962 us; speedup vs baseline: 4.4430x; 4.4430x over previous
//
#include <hip/hip_runtime.h>
#include <hip/hip_bf16.h>

#define N_NODES 50000
#define DIM 256
#define N_EDGES 320000
#define BM 32
#define LDA 264   // bf16 elements per LDS row: 256 + 8 pad -> 528B stride, 2-way bank alias (free)

typedef __attribute__((ext_vector_type(8))) short short8;
typedef __attribute__((ext_vector_type(4))) float f32x4;
typedef __attribute__((ext_vector_type(4))) unsigned short ushort4v;

struct alignas(8) Pay { int idx; float nrm; };

static __device__ __forceinline__ unsigned short f2bf(float f) {
  unsigned int u = __float_as_uint(f);
  return (unsigned short)((u + 0x7FFFu + ((u >> 16) & 1u)) >> 16);  // RNE
}

__global__ __launch_bounds__(256) void k_count(const int* __restrict__ dst,
                                               int* __restrict__ deg) {
  int e = blockIdx.x * 256 + threadIdx.x;
  if (e < N_EDGES) atomicAdd(&deg[dst[e]], 1);
}

__global__ __launch_bounds__(256) void k_dinv(const int* __restrict__ deg,
                                              float* __restrict__ dinv) {
  int i = blockIdx.x * 256 + threadIdx.x;
  if (i < N_NODES) dinv[i] = rsqrtf((float)(deg[i] + 1));  // +1 self-loop; always > 0
}

__global__ __launch_bounds__(256) void k_wconv(const float* __restrict__ W,
                                               unsigned short* __restrict__ wbf) {
  int i = blockIdx.x * 256 + threadIdx.x;  // quad index, 16384 total
  const float4 v = ((const float4*)W)[i];
  ushort4v r;
  r.x = f2bf(v.x); r.y = f2bf(v.y); r.z = f2bf(v.z); r.w = f2bf(v.w);
  *(ushort4v*)(wbf + i * 4) = r;
}

// Single-block exclusive prefix scan over deg[0..N_NODES) -> offs, cursor.
// 1024 threads, serial over chunks with carried base. ~49 iterations.
__global__ __launch_bounds__(1024) void k_scan(const int* __restrict__ deg,
                                               int* __restrict__ offs,
                                               int* __restrict__ cursor) {
  __shared__ int wsum[16];
  __shared__ int wbase[16];
  __shared__ int ctot;
  const int tid = threadIdx.x, lane = tid & 63, wv = tid >> 6;
  int carry = 0;
  for (int base = 0; base < N_NODES; base += 1024) {
    int i = base + tid;
    int v = (i < N_NODES) ? deg[i] : 0;
    int x = v;
#pragma unroll
    for (int off = 1; off < 64; off <<= 1) {
      int y = __shfl_up(x, off, 64);
      if (lane >= off) x += y;
    }
    if (lane == 63) wsum[wv] = x;
    __syncthreads();
    if (tid < 16) {
      int s = wsum[tid];
#pragma unroll
      for (int off = 1; off < 16; off <<= 1) {
        int y = __shfl_up(s, off, 64);
        if (tid >= off) s += y;
      }
      wbase[tid] = s - wsum[tid];
      if (tid == 15) ctot = s;
    }
    __syncthreads();
    if (i < N_NODES) {
      int excl = carry + wbase[wv] + (x - v);
      offs[i] = excl;
      cursor[i] = excl;
    }
    carry += ctot;
    __syncthreads();  // protect wsum/ctot before next chunk
  }
  if (tid == 0) offs[N_NODES] = carry;
}

// Bucket edges by dst: payload = {emb row of src, norm}.
__global__ __launch_bounds__(256) void k_scatter(const int* __restrict__ src,
                                                 const int* __restrict__ dst,
                                                 const int* __restrict__ nodes,
                                                 const float* __restrict__ dinv,
                                                 int* __restrict__ cursor,
                                                 Pay* __restrict__ pay) {
  int e = blockIdx.x * 256 + threadIdx.x;
  if (e >= N_EDGES) return;
  int s = src[e], d = dst[e];
  int pos = atomicAdd(&cursor[d], 1);
  Pay p;
  p.idx = nodes[s];
  p.nrm = dinv[s] * dinv[d];
  pay[pos] = p;
}

// One wave per dst node: register-accumulate incoming rows + self-loop, single write.
__global__ __launch_bounds__(256) void k_gather(const int* __restrict__ nodes,
                                                const float* __restrict__ dinv,
                                                const float* __restrict__ emb,
                                                const int* __restrict__ offs,
                                                const Pay* __restrict__ pay,
                                                float* __restrict__ out) {
  int d = (blockIdx.x * 256 + threadIdx.x) >> 6;
  if (d >= N_NODES) return;
  const int lane = threadIdx.x & 63;
  const float dd = dinv[d];
  const int nr = nodes[d];
  float4 v = ((const float4*)(emb + (size_t)nr * DIM))[lane];
  const float sl = dd * dd;
  float4 acc = make_float4(v.x * sl, v.y * sl, v.z * sl, v.w * sl);
  const int jb = offs[d], je = offs[d + 1];
  for (int j = jb; j < je; ++j) {
    Pay p = pay[j];
    const float4 w = ((const float4*)(emb + (size_t)p.idx * DIM))[lane];
    acc.x += w.x * p.nrm;
    acc.y += w.y * p.nrm;
    acc.z += w.z * p.nrm;
    acc.w += w.w * p.nrm;
  }
  ((float4*)(out + (size_t)d * DIM))[lane] = acc;
}

// In-place: out = relu(agg @ W^T + b). BM=32 rows x 256 cols per block, 4 waves.
// C/D: col = lane&15, row = (lane>>4)*4 + reg   [guide-verified m89/m91]
__global__ __launch_bounds__(256) void k_gemm(const float* agg,
                                              const unsigned short* __restrict__ wbf,
                                              const float* __restrict__ bias,
                                              float* out) {
  __shared__ unsigned short As[BM * LDA];
  const int tid = threadIdx.x;
  const int row0 = blockIdx.x * BM;

  // Stage A tile (32 x 256 fp32 -> bf16). 8 threads per row, 8 float4 each.
  {
    int r = tid >> 3;
    int grow = row0 + r;
    const float4* srcp = (const float4*)(agg + (size_t)grow * DIM);
    unsigned short* lrow = &As[r * LDA];
#pragma unroll
    for (int j = 0; j < 8; ++j) {
      int c4 = (tid & 7) + j * 8;
      float4 v = make_float4(0.f, 0.f, 0.f, 0.f);
      if (grow < N_NODES) v = srcp[c4];
      int c = c4 * 4;
      lrow[c] = f2bf(v.x); lrow[c + 1] = f2bf(v.y);
      lrow[c + 2] = f2bf(v.z); lrow[c + 3] = f2bf(v.w);
    }
  }
  __syncthreads();

  const int wv = tid >> 6, lane = tid & 63;
  const int l15 = lane & 15, kq = lane >> 4;
  const int cb = wv * 64;
  f32x4 acc[2][4] = {};
#pragma unroll
  for (int ks = 0; ks < 8; ++ks) {
    const int kb = ks * 32 + kq * 8;
    short8 a0 = *(const short8*)&As[l15 * LDA + kb];
    short8 a1 = *(const short8*)&As[(16 + l15) * LDA + kb];
    short8 b[4];
#pragma unroll
    for (int f = 0; f < 4; ++f)
      b[f] = *(const short8*)(wbf + (cb + f * 16 + l15) * 256 + kb);
#pragma unroll
    for (int f = 0; f < 4; ++f) {
      acc[0][f] = __builtin_amdgcn_mfma_f32_16x16x32_bf16(a0, b[f], acc[0][f], 0, 0, 0);
      acc[1][f] = __builtin_amdgcn_mfma_f32_16x16x32_bf16(a1, b[f], acc[1][f], 0, 0, 0);
    }
  }
  // Epilogue: + bias, relu, store fp32.
#pragma unroll
  for (int h = 0; h < 2; ++h) {
    int rb = row0 + h * 16 + kq * 4;
#pragma unroll
    for (int f = 0; f < 4; ++f) {
      int col = cb + f * 16 + l15;
      float bv = bias[col];
#pragma unroll
      for (int g = 0; g < 4; ++g) {
        int r = rb + g;
        if (r < N_NODES) {
          float v = acc[h][f][g] + bv;
          out[(size_t)r * DIM + col] = fmaxf(v, 0.f);
        }
      }
    }
  }
}

extern "C" void kernel_launch(void* const* d_in, const int* in_sizes, int n_in,
                              void* d_out, int out_size, void* d_ws, size_t ws_size,
                              hipStream_t stream) {
  const int* nodes = (const int*)d_in[0];
  const int* edges = (const int*)d_in[1];
  const float* emb = (const float*)d_in[2];
  const float* W = (const float*)d_in[3];
  const float* bias = (const float*)d_in[4];
  float* out = (float*)d_out;

  // Workspace layout (16B-aligned blocks):
  //   deg    int[50016]      @ 0
  //   dinv   float[50016]    @ 200064
  //   offs   int[50001..]    @ 400128
  //   cursor int[50000..]    @ 600192
  //   wbf    ushort[65536]   @ 800256
  //   pay    Pay[320000]     @ 931328   (end ~3.49 MB)
  int* deg = (int*)d_ws;
  float* dinv = (float*)((char*)d_ws + 200064);
  int* offs = (int*)((char*)d_ws + 400128);
  int* cursor = (int*)((char*)d_ws + 600192);
  unsigned short* wbf = (unsigned short*)((char*)d_ws + 800256);
  Pay* pay = (Pay*)((char*)d_ws + 931328);

  const int* srcp = edges;             // edges[0]
  const int* dstp = edges + N_EDGES;   // edges[1]

  hipMemsetAsync(deg, 0, N_NODES * sizeof(int), stream);
  k_count<<<(N_EDGES + 255) / 256, 256, 0, stream>>>(dstp, deg);
  k_dinv<<<(N_NODES + 255) / 256, 256, 0, stream>>>(deg, dinv);
  k_wconv<<<64, 256, 0, stream>>>(W, wbf);
  k_scan<<<1, 1024, 0, stream>>>(deg, offs, cursor);
  k_scatter<<<(N_EDGES + 255) / 256, 256, 0, stream>>>(srcp, dstp, nodes, dinv, cursor, pay);
  k_gather<<<(N_NODES * 64 + 255) / 256, 256, 0, stream>>>(nodes, dinv, emb, offs, pay, out);
  k_gemm<<<(N_NODES + BM - 1) / BM, 256, 0, stream>>>(out, wbf, bias, out);
}

// Round 3
// 256.008 us; speedup vs baseline: 4.8414x; 1.0897x over previous
//
#include <hip/hip_runtime.h>
#include <hip/hip_bf16.h>

#define N_NODES 50000
#define DIM 256
#define N_EDGES 320000
#define BM 32
#define LDA 264     // bf16 elems per LDS row: 256+8 pad (528B stride)
#define SCAN_NB 196 // ceil(50000/256)

typedef __attribute__((ext_vector_type(8))) short short8;
typedef __attribute__((ext_vector_type(4))) float f32x4;
typedef __attribute__((ext_vector_type(4))) unsigned short ushort4v;

struct alignas(8) Pay { int idx; float nrm; };

static __device__ __forceinline__ unsigned short f2bf(float f) {
  unsigned int u = __float_as_uint(f);
  return (unsigned short)((u + 0x7FFFu + ((u >> 16) & 1u)) >> 16);  // RNE
}
static __device__ __forceinline__ float bf2f(unsigned short s) {
  return __uint_as_float(((unsigned int)s) << 16);
}

__global__ __launch_bounds__(256) void k_count(const int* __restrict__ dst,
                                               int* __restrict__ deg) {
  int e = blockIdx.x * 256 + threadIdx.x;
  if (e < N_EDGES) atomicAdd(&deg[dst[e]], 1);
}

__global__ __launch_bounds__(256) void k_wconv(const float* __restrict__ W,
                                               unsigned short* __restrict__ wbf) {
  int i = blockIdx.x * 256 + threadIdx.x;  // quad index, 16384 total
  const float4 v = ((const float4*)W)[i];
  ushort4v r;
  r.x = f2bf(v.x); r.y = f2bf(v.y); r.z = f2bf(v.z); r.w = f2bf(v.w);
  *(ushort4v*)(wbf + i * 4) = r;
}

__global__ __launch_bounds__(256) void k_embconv(const float* __restrict__ emb,
                                                 unsigned short* __restrict__ ebf) {
  int i = blockIdx.x * 256 + threadIdx.x;  // quad index, 3.2M total
  const float4 v = ((const float4*)emb)[i];
  ushort4v r;
  r.x = f2bf(v.x); r.y = f2bf(v.y); r.z = f2bf(v.z); r.w = f2bf(v.w);
  *(ushort4v*)(ebf + i * 4) = r;
}

// ---- hierarchical exclusive scan of deg -> offs/cursor (3 tiny kernels) ----
__global__ __launch_bounds__(256) void k_scan1(const int* __restrict__ deg,
                                               int* __restrict__ bsum) {
  int i = blockIdx.x * 256 + threadIdx.x;
  int v = (i < N_NODES) ? deg[i] : 0;
#pragma unroll
  for (int off = 32; off; off >>= 1) v += __shfl_xor(v, off, 64);
  __shared__ int ws[4];
  if ((threadIdx.x & 63) == 0) ws[threadIdx.x >> 6] = v;
  __syncthreads();
  if (threadIdx.x == 0) bsum[blockIdx.x] = ws[0] + ws[1] + ws[2] + ws[3];
}

__global__ __launch_bounds__(256) void k_scan2(const int* __restrict__ bsum,
                                               int* __restrict__ bbase) {
  __shared__ int wsum[4], wb[4];
  int tid = threadIdx.x, lane = tid & 63, wv = tid >> 6;
  int v = (tid < SCAN_NB) ? bsum[tid] : 0;
  int x = v;
#pragma unroll
  for (int off = 1; off < 64; off <<= 1) {
    int y = __shfl_up(x, off, 64);
    if (lane >= off) x += y;
  }
  if (lane == 63) wsum[wv] = x;
  __syncthreads();
  if (tid == 0) { int s = 0; for (int k = 0; k < 4; ++k) { int t = wsum[k]; wb[k] = s; s += t; } }
  __syncthreads();
  if (tid < SCAN_NB) bbase[tid] = wb[wv] + (x - v);
}

__global__ __launch_bounds__(256) void k_scan3(const int* __restrict__ deg,
                                               const int* __restrict__ bbase,
                                               int* __restrict__ offs,
                                               int* __restrict__ cursor,
                                               float* __restrict__ dinv) {
  __shared__ int wsum[4], wb[4];
  int tid = threadIdx.x, lane = tid & 63, wv = tid >> 6;
  int i = blockIdx.x * 256 + tid;
  int v = (i < N_NODES) ? deg[i] : 0;
  int x = v;
#pragma unroll
  for (int off = 1; off < 64; off <<= 1) {
    int y = __shfl_up(x, off, 64);
    if (lane >= off) x += y;
  }
  if (lane == 63) wsum[wv] = x;
  __syncthreads();
  if (tid == 0) { int s = 0; for (int k = 0; k < 4; ++k) { int t = wsum[k]; wb[k] = s; s += t; } }
  __syncthreads();
  if (i < N_NODES) {
    int excl = bbase[blockIdx.x] + wb[wv] + (x - v);
    offs[i] = excl;
    cursor[i] = excl;
    dinv[i] = rsqrtf((float)(v + 1));  // +1 self-loop
  }
  if (blockIdx.x == 0 && tid == 0) offs[N_NODES] = N_EDGES;
}

// Bucket edges by dst: payload = {emb row of src, norm}.
__global__ __launch_bounds__(256) void k_scatter(const int* __restrict__ src,
                                                 const int* __restrict__ dst,
                                                 const int* __restrict__ nodes,
                                                 const float* __restrict__ dinv,
                                                 int* __restrict__ cursor,
                                                 Pay* __restrict__ pay) {
  int e = blockIdx.x * 256 + threadIdx.x;
  if (e >= N_EDGES) return;
  int s = src[e], d = dst[e];
  int pos = atomicAdd(&cursor[d], 1);
  Pay p;
  p.idx = nodes[s];
  p.nrm = dinv[s] * dinv[d];
  pay[pos] = p;
}

// Fused aggregate + GEMM: block = BM=32 output rows x 256 cols, 4 waves.
// Phase 1: wave wv gathers rows wv*8..wv*8+7 (register fp32 acc), writes bf16 to LDS.
// Phase 2: MFMA 16x16x32 bf16; C/D: col=lane&15, row=(lane>>4)*4+reg [m89/m91].
template <int EMBBF>
__global__ __launch_bounds__(256) void k_fused(const int* __restrict__ nodes,
                                               const float* __restrict__ dinv,
                                               const void* __restrict__ embv,
                                               const int* __restrict__ offs,
                                               const Pay* __restrict__ pay,
                                               const unsigned short* __restrict__ wbf,
                                               const float* __restrict__ bias,
                                               float* __restrict__ out) {
  __shared__ unsigned short As[BM * LDA];
  const int tid = threadIdx.x;
  const int wv = tid >> 6, lane = tid & 63;
  const int row0 = blockIdx.x * BM;

#pragma unroll 1
  for (int j = 0; j < 8; ++j) {
    const int r = wv * 8 + j;
    const int d = row0 + r;
    float4 acc = make_float4(0.f, 0.f, 0.f, 0.f);
    if (d < N_NODES) {
      const float dd = dinv[d];
      const float sl = dd * dd;
      const int nr = nodes[d];
      if (EMBBF) {
        const ushort4v s4 = ((const ushort4v*)((const unsigned short*)embv + (size_t)nr * DIM))[lane];
        acc.x = bf2f(s4.x) * sl; acc.y = bf2f(s4.y) * sl;
        acc.z = bf2f(s4.z) * sl; acc.w = bf2f(s4.w) * sl;
      } else {
        const float4 v = ((const float4*)((const float*)embv + (size_t)nr * DIM))[lane];
        acc.x = v.x * sl; acc.y = v.y * sl; acc.z = v.z * sl; acc.w = v.w * sl;
      }
      const int jb = offs[d], je = offs[d + 1];
      for (int e = jb; e < je; ++e) {
        const Pay p = pay[e];
        if (EMBBF) {
          const ushort4v s4 = ((const ushort4v*)((const unsigned short*)embv + (size_t)p.idx * DIM))[lane];
          acc.x += bf2f(s4.x) * p.nrm; acc.y += bf2f(s4.y) * p.nrm;
          acc.z += bf2f(s4.z) * p.nrm; acc.w += bf2f(s4.w) * p.nrm;
        } else {
          const float4 w = ((const float4*)((const float*)embv + (size_t)p.idx * DIM))[lane];
          acc.x += w.x * p.nrm; acc.y += w.y * p.nrm;
          acc.z += w.z * p.nrm; acc.w += w.w * p.nrm;
        }
      }
    }
    ushort4v o;
    o.x = f2bf(acc.x); o.y = f2bf(acc.y); o.z = f2bf(acc.z); o.w = f2bf(acc.w);
    *(ushort4v*)&As[r * LDA + lane * 4] = o;
  }
  __syncthreads();

  const int l15 = lane & 15, kq = lane >> 4;
  const int cb = wv * 64;
  f32x4 acc[2][4] = {};
#pragma unroll
  for (int ks = 0; ks < 8; ++ks) {
    const int kb = ks * 32 + kq * 8;
    short8 a0 = *(const short8*)&As[l15 * LDA + kb];
    short8 a1 = *(const short8*)&As[(16 + l15) * LDA + kb];
    short8 b[4];
#pragma unroll
    for (int f = 0; f < 4; ++f)
      b[f] = *(const short8*)(wbf + (cb + f * 16 + l15) * 256 + kb);
#pragma unroll
    for (int f = 0; f < 4; ++f) {
      acc[0][f] = __builtin_amdgcn_mfma_f32_16x16x32_bf16(a0, b[f], acc[0][f], 0, 0, 0);
      acc[1][f] = __builtin_amdgcn_mfma_f32_16x16x32_bf16(a1, b[f], acc[1][f], 0, 0, 0);
    }
  }
#pragma unroll
  for (int h = 0; h < 2; ++h) {
    int rb = row0 + h * 16 + kq * 4;
#pragma unroll
    for (int f = 0; f < 4; ++f) {
      int col = cb + f * 16 + l15;
      float bv = bias[col];
#pragma unroll
      for (int g = 0; g < 4; ++g) {
        int r = rb + g;
        if (r < N_NODES) {
          float v = acc[h][f][g] + bv;
          out[(size_t)r * DIM + col] = fmaxf(v, 0.f);
        }
      }
    }
  }
}

extern "C" void kernel_launch(void* const* d_in, const int* in_sizes, int n_in,
                              void* d_out, int out_size, void* d_ws, size_t ws_size,
                              hipStream_t stream) {
  const int* nodes = (const int*)d_in[0];
  const int* edges = (const int*)d_in[1];
  const float* emb = (const float*)d_in[2];
  const float* W = (const float*)d_in[3];
  const float* bias = (const float*)d_in[4];
  float* out = (float*)d_out;

  // Workspace layout (bytes):
  //   deg    @ 0        (200704)
  //   dinv   @ 200704   (200704)
  //   offs   @ 401408   (200704)
  //   cursor @ 602112   (200704)
  //   bsum   @ 802816   (1024)
  //   bbase  @ 803840   (1024)
  //   wbf    @ 804864   (131072)
  //   pay    @ 935936   (2560000)
  //   embbf  @ 3495936  (25600000)  -> total 29095936
  int* deg = (int*)d_ws;
  float* dinv = (float*)((char*)d_ws + 200704);
  int* offs = (int*)((char*)d_ws + 401408);
  int* cursor = (int*)((char*)d_ws + 602112);
  int* bsum = (int*)((char*)d_ws + 802816);
  int* bbase = (int*)((char*)d_ws + 803840);
  unsigned short* wbf = (unsigned short*)((char*)d_ws + 804864);
  Pay* pay = (Pay*)((char*)d_ws + 935936);
  unsigned short* embbf = (unsigned short*)((char*)d_ws + 3495936);
  const bool use_bf16 = ws_size >= 29095936ull;

  const int* srcp = edges;             // edges[0]
  const int* dstp = edges + N_EDGES;   // edges[1]

  hipMemsetAsync(deg, 0, N_NODES * sizeof(int), stream);
  k_count<<<(N_EDGES + 255) / 256, 256, 0, stream>>>(dstp, deg);
  k_wconv<<<64, 256, 0, stream>>>(W, wbf);
  k_scan1<<<SCAN_NB, 256, 0, stream>>>(deg, bsum);
  k_scan2<<<1, 256, 0, stream>>>(bsum, bbase);
  k_scan3<<<SCAN_NB, 256, 0, stream>>>(deg, bbase, offs, cursor, dinv);
  if (use_bf16) k_embconv<<<12500, 256, 0, stream>>>(emb, embbf);
  k_scatter<<<(N_EDGES + 255) / 256, 256, 0, stream>>>(srcp, dstp, nodes, dinv, cursor, pay);
  const int nblk = (N_NODES + BM - 1) / BM;
  if (use_bf16)
    k_fused<1><<<nblk, 256, 0, stream>>>(nodes, dinv, embbf, offs, pay, wbf, bias, out);
  else
    k_fused<0><<<nblk, 256, 0, stream>>>(nodes, dinv, emb, offs, pay, wbf, bias, out);
}

// Round 5
// 216.478 us; speedup vs baseline: 5.7255x; 1.1826x over previous
//
#include <hip/hip_runtime.h>
#include <hip/hip_bf16.h>

#define N_NODES 50000
#define DIM 256
#define N_EDGES 320000
#define BM 32
#define LDA 264     // bf16 elems per LDS row: 256+8 pad (528B stride, 2-way alias = free)
#define SCAN_NB 196 // ceil(50000/256)

typedef __attribute__((ext_vector_type(8))) short short8;
typedef __attribute__((ext_vector_type(4))) float f32x4;
typedef __attribute__((ext_vector_type(4))) unsigned short ushort4v;

struct alignas(8) Pay { int idx; float nrm; };

static __device__ __forceinline__ unsigned short f2bf(float f) {
  unsigned int u = __float_as_uint(f);
  return (unsigned short)((u + 0x7FFFu + ((u >> 16) & 1u)) >> 16);  // RNE
}
static __device__ __forceinline__ float bf2f(unsigned short s) {
  return __uint_as_float(((unsigned int)s) << 16);
}

// Fused independent prep: [0,EB) emb->bf16, [EB,EB+64) W->bf16, rest: degree count.
// FULL=0 skips embconv (fp32 fallback path).
template <int FULL>
__global__ __launch_bounds__(256) void k_misc(const float* __restrict__ emb,
                                              unsigned short* __restrict__ ebf,
                                              const float* __restrict__ W,
                                              unsigned short* __restrict__ wbf,
                                              const int* __restrict__ dst,
                                              int* __restrict__ deg) {
  const int EB = FULL ? 12500 : 0;
  int b = blockIdx.x;
  if (FULL && b < EB) {
    int i = b * 256 + threadIdx.x;
    const float4 v = ((const float4*)emb)[i];
    ushort4v r;
    r.x = f2bf(v.x); r.y = f2bf(v.y); r.z = f2bf(v.z); r.w = f2bf(v.w);
    *(ushort4v*)(ebf + (size_t)i * 4) = r;
  } else if (b < EB + 64) {
    int i = (b - EB) * 256 + threadIdx.x;
    const float4 v = ((const float4*)W)[i];
    ushort4v r;
    r.x = f2bf(v.x); r.y = f2bf(v.y); r.z = f2bf(v.z); r.w = f2bf(v.w);
    *(ushort4v*)(wbf + (size_t)i * 4) = r;
  } else {
    int e = (b - EB - 64) * 256 + threadIdx.x;
    if (e < N_EDGES) atomicAdd(&deg[dst[e]], 1);
  }
}

// ---- hierarchical exclusive scan of deg -> offs/cursor/dinv ----
__global__ __launch_bounds__(256) void k_scan1(const int* __restrict__ deg,
                                               int* __restrict__ bsum) {
  int i = blockIdx.x * 256 + threadIdx.x;
  int v = (i < N_NODES) ? deg[i] : 0;
#pragma unroll
  for (int off = 32; off; off >>= 1) v += __shfl_xor(v, off, 64);
  __shared__ int ws[4];
  if ((threadIdx.x & 63) == 0) ws[threadIdx.x >> 6] = v;
  __syncthreads();
  if (threadIdx.x == 0) bsum[blockIdx.x] = ws[0] + ws[1] + ws[2] + ws[3];
}

__global__ __launch_bounds__(256) void k_scan2(const int* __restrict__ bsum,
                                               int* __restrict__ bbase) {
  __shared__ int wsum[4], wb[4];
  int tid = threadIdx.x, lane = tid & 63, wv = tid >> 6;
  int v = (tid < SCAN_NB) ? bsum[tid] : 0;
  int x = v;
#pragma unroll
  for (int off = 1; off < 64; off <<= 1) {
    int y = __shfl_up(x, off, 64);
    if (lane >= off) x += y;
  }
  if (lane == 63) wsum[wv] = x;
  __syncthreads();
  if (tid == 0) { int s = 0; for (int k = 0; k < 4; ++k) { int t = wsum[k]; wb[k] = s; s += t; } }
  __syncthreads();
  if (tid < SCAN_NB) bbase[tid] = wb[wv] + (x - v);
}

__global__ __launch_bounds__(256) void k_scan3(const int* __restrict__ deg,
                                               const int* __restrict__ bbase,
                                               int* __restrict__ offs,
                                               int* __restrict__ cursor,
                                               float* __restrict__ dinv) {
  __shared__ int wsum[4], wb[4];
  int tid = threadIdx.x, lane = tid & 63, wv = tid >> 6;
  int i = blockIdx.x * 256 + tid;
  int v = (i < N_NODES) ? deg[i] : 0;
  int x = v;
#pragma unroll
  for (int off = 1; off < 64; off <<= 1) {
    int y = __shfl_up(x, off, 64);
    if (lane >= off) x += y;
  }
  if (lane == 63) wsum[wv] = x;
  __syncthreads();
  if (tid == 0) { int s = 0; for (int k = 0; k < 4; ++k) { int t = wsum[k]; wb[k] = s; s += t; } }
  __syncthreads();
  if (i < N_NODES) {
    int excl = bbase[blockIdx.x] + wb[wv] + (x - v);
    offs[i] = excl;
    cursor[i] = excl;
    dinv[i] = rsqrtf((float)(v + 1));  // +1 self-loop
  }
  if (blockIdx.x == 0 && tid == 0) offs[N_NODES] = N_EDGES;
}

// Bucket edges by dst: payload = {emb row of src, norm}.
__global__ __launch_bounds__(256) void k_scatter(const int* __restrict__ src,
                                                 const int* __restrict__ dst,
                                                 const int* __restrict__ nodes,
                                                 const float* __restrict__ dinv,
                                                 int* __restrict__ cursor,
                                                 Pay* __restrict__ pay) {
  int e = blockIdx.x * 256 + threadIdx.x;
  if (e >= N_EDGES) return;
  int s = src[e], d = dst[e];
  int pos = atomicAdd(&cursor[d], 1);
  Pay p;
  p.idx = nodes[s];
  p.nrm = dinv[s] * dinv[d];
  pay[pos] = p;
}

// One wave per dst node, 4-way MLP unroll; bf16 in (EMBBF) / fp32 in, bf16 agg out.
template <int EMBBF>
__global__ __launch_bounds__(256) void k_gather(const int* __restrict__ nodes,
                                                const float* __restrict__ dinv,
                                                const void* __restrict__ embv,
                                                const int* __restrict__ offs,
                                                const Pay* __restrict__ pay,
                                                unsigned short* __restrict__ agg) {
  int d = (blockIdx.x * 256 + threadIdx.x) >> 6;
  if (d >= N_NODES) return;
  const int lane = threadIdx.x & 63;
  const float dd = dinv[d];
  const int nr = nodes[d];
  const float sl = dd * dd;
  float4 acc;
  if (EMBBF) {
    const ushort4v s4 = ((const ushort4v*)((const unsigned short*)embv + (size_t)nr * DIM))[lane];
    acc = make_float4(bf2f(s4.x) * sl, bf2f(s4.y) * sl, bf2f(s4.z) * sl, bf2f(s4.w) * sl);
  } else {
    const float4 v = ((const float4*)((const float*)embv + (size_t)nr * DIM))[lane];
    acc = make_float4(v.x * sl, v.y * sl, v.z * sl, v.w * sl);
  }
  const int jb = offs[d], je = offs[d + 1];
  int e = jb;
  for (; e + 4 <= je; e += 4) {
    const Pay p0 = pay[e], p1 = pay[e + 1], p2 = pay[e + 2], p3 = pay[e + 3];
    if (EMBBF) {
      const unsigned short* eb = (const unsigned short*)embv;
      const ushort4v w0 = ((const ushort4v*)(eb + (size_t)p0.idx * DIM))[lane];
      const ushort4v w1 = ((const ushort4v*)(eb + (size_t)p1.idx * DIM))[lane];
      const ushort4v w2 = ((const ushort4v*)(eb + (size_t)p2.idx * DIM))[lane];
      const ushort4v w3 = ((const ushort4v*)(eb + (size_t)p3.idx * DIM))[lane];
      acc.x += bf2f(w0.x) * p0.nrm + bf2f(w1.x) * p1.nrm + bf2f(w2.x) * p2.nrm + bf2f(w3.x) * p3.nrm;
      acc.y += bf2f(w0.y) * p0.nrm + bf2f(w1.y) * p1.nrm + bf2f(w2.y) * p2.nrm + bf2f(w3.y) * p3.nrm;
      acc.z += bf2f(w0.z) * p0.nrm + bf2f(w1.z) * p1.nrm + bf2f(w2.z) * p2.nrm + bf2f(w3.z) * p3.nrm;
      acc.w += bf2f(w0.w) * p0.nrm + bf2f(w1.w) * p1.nrm + bf2f(w2.w) * p2.nrm + bf2f(w3.w) * p3.nrm;
    } else {
      const float* ef = (const float*)embv;
      const float4 w0 = ((const float4*)(ef + (size_t)p0.idx * DIM))[lane];
      const float4 w1 = ((const float4*)(ef + (size_t)p1.idx * DIM))[lane];
      const float4 w2 = ((const float4*)(ef + (size_t)p2.idx * DIM))[lane];
      const float4 w3 = ((const float4*)(ef + (size_t)p3.idx * DIM))[lane];
      acc.x += w0.x * p0.nrm + w1.x * p1.nrm + w2.x * p2.nrm + w3.x * p3.nrm;
      acc.y += w0.y * p0.nrm + w1.y * p1.nrm + w2.y * p2.nrm + w3.y * p3.nrm;
      acc.z += w0.z * p0.nrm + w1.z * p1.nrm + w2.z * p2.nrm + w3.z * p3.nrm;
      acc.w += w0.w * p0.nrm + w1.w * p1.nrm + w2.w * p2.nrm + w3.w * p3.nrm;
    }
  }
  for (; e < je; ++e) {
    const Pay p = pay[e];
    if (EMBBF) {
      const ushort4v w = ((const ushort4v*)((const unsigned short*)embv + (size_t)p.idx * DIM))[lane];
      acc.x += bf2f(w.x) * p.nrm; acc.y += bf2f(w.y) * p.nrm;
      acc.z += bf2f(w.z) * p.nrm; acc.w += bf2f(w.w) * p.nrm;
    } else {
      const float4 w = ((const float4*)((const float*)embv + (size_t)p.idx * DIM))[lane];
      acc.x += w.x * p.nrm; acc.y += w.y * p.nrm;
      acc.z += w.z * p.nrm; acc.w += w.w * p.nrm;
    }
  }
  ushort4v o;
  o.x = f2bf(acc.x); o.y = f2bf(acc.y); o.z = f2bf(acc.z); o.w = f2bf(acc.w);
  ((ushort4v*)(agg + (size_t)d * DIM))[lane] = o;
}

// out = relu(agg_bf16 @ W^T + b). BM=32 x 256 per block, 4 waves.
// C/D: col=lane&15, row=(lane>>4)*4+reg [guide-verified m89/m91]
__global__ __launch_bounds__(256) void k_gemm(const unsigned short* __restrict__ agg,
                                              const unsigned short* __restrict__ wbf,
                                              const float* __restrict__ bias,
                                              float* __restrict__ out) {
  __shared__ unsigned short As[BM * LDA];
  const int tid = threadIdx.x;
  const int row0 = blockIdx.x * BM;

  // Stage A tile: 32 rows x 512B; 32 threads/row x 16B, 4 passes of 8 rows.
  {
    const int c = (tid & 31) * 8;
    const int rb = tid >> 5;
#pragma unroll
    for (int p = 0; p < 4; ++p) {
      const int r = rb + p * 8;
      const int grow = row0 + r;
      short8 v = {};
      if (grow < N_NODES) v = *(const short8*)(agg + (size_t)grow * DIM + c);
      *(short8*)&As[r * LDA + c] = v;
    }
  }
  __syncthreads();

  const int wv = tid >> 6, lane = tid & 63;
  const int l15 = lane & 15, kq = lane >> 4;
  const int cb = wv * 64;
  f32x4 acc[2][4] = {};
#pragma unroll
  for (int ks = 0; ks < 8; ++ks) {
    const int kb = ks * 32 + kq * 8;
    short8 a0 = *(const short8*)&As[l15 * LDA + kb];
    short8 a1 = *(const short8*)&As[(16 + l15) * LDA + kb];
    short8 b[4];
#pragma unroll
    for (int f = 0; f < 4; ++f)
      b[f] = *(const short8*)(wbf + (cb + f * 16 + l15) * 256 + kb);
#pragma unroll
    for (int f = 0; f < 4; ++f) {
      acc[0][f] = __builtin_amdgcn_mfma_f32_16x16x32_bf16(a0, b[f], acc[0][f], 0, 0, 0);
      acc[1][f] = __builtin_amdgcn_mfma_f32_16x16x32_bf16(a1, b[f], acc[1][f], 0, 0, 0);
    }
  }
#pragma unroll
  for (int h = 0; h < 2; ++h) {
    int rb = row0 + h * 16 + kq * 4;
#pragma unroll
    for (int f = 0; f < 4; ++f) {
      int col = cb + f * 16 + l15;
      float bv = bias[col];
#pragma unroll
      for (int g = 0; g < 4; ++g) {
        int r = rb + g;
        if (r < N_NODES) {
          float v = acc[h][f][g] + bv;
          __builtin_nontemporal_store(fmaxf(v, 0.f), &out[(size_t)r * DIM + col]);
        }
      }
    }
  }
}

extern "C" void kernel_launch(void* const* d_in, const int* in_sizes, int n_in,
                              void* d_out, int out_size, void* d_ws, size_t ws_size,
                              hipStream_t stream) {
  const int* nodes = (const int*)d_in[0];
  const int* edges = (const int*)d_in[1];
  const float* emb = (const float*)d_in[2];
  const float* W = (const float*)d_in[3];
  const float* bias = (const float*)d_in[4];
  float* out = (float*)d_out;

  // Workspace layout (bytes):
  //   deg    @ 0        (200704)
  //   dinv   @ 200704   (200704)
  //   offs   @ 401408   (200704)
  //   cursor @ 602112   (200704)
  //   bsum   @ 802816   (1024)
  //   bbase  @ 803840   (1024)
  //   wbf    @ 804864   (131072)
  //   pay    @ 935936   (2560000)
  //   ebf    @ 3495936  (25600000)
  //   agg    @ 29095936 (25600000)  -> total 54695936
  int* deg = (int*)d_ws;
  float* dinv = (float*)((char*)d_ws + 200704);
  int* offs = (int*)((char*)d_ws + 401408);
  int* cursor = (int*)((char*)d_ws + 602112);
  int* bsum = (int*)((char*)d_ws + 802816);
  int* bbase = (int*)((char*)d_ws + 803840);
  unsigned short* wbf = (unsigned short*)((char*)d_ws + 804864);
  Pay* pay = (Pay*)((char*)d_ws + 935936);
  unsigned short* ebf = (unsigned short*)((char*)d_ws + 3495936);
  unsigned short* agg = (unsigned short*)((char*)d_ws + 29095936);
  const bool full = ws_size >= 54695936ull;
  if (!full) agg = (unsigned short*)((char*)d_ws + 3495936);  // reuse ebf slot

  const int* srcp = edges;             // edges[0]
  const int* dstp = edges + N_EDGES;   // edges[1]

  hipMemsetAsync(deg, 0, N_NODES * sizeof(int), stream);
  if (full)
    k_misc<1><<<12500 + 64 + 1250, 256, 0, stream>>>(emb, ebf, W, wbf, dstp, deg);
  else
    k_misc<0><<<64 + 1250, 256, 0, stream>>>(emb, ebf, W, wbf, dstp, deg);
  k_scan1<<<SCAN_NB, 256, 0, stream>>>(deg, bsum);
  k_scan2<<<1, 256, 0, stream>>>(bsum, bbase);
  k_scan3<<<SCAN_NB, 256, 0, stream>>>(deg, bbase, offs, cursor, dinv);
  k_scatter<<<(N_EDGES + 255) / 256, 256, 0, stream>>>(srcp, dstp, nodes, dinv, cursor, pay);
  if (full)
    k_gather<1><<<(N_NODES * 64 + 255) / 256, 256, 0, stream>>>(nodes, dinv, ebf, offs, pay, agg);
  else
    k_gather<0><<<(N_NODES * 64 + 255) / 256, 256, 0, stream>>>(nodes, dinv, emb, offs, pay, agg);
  k_gemm<<<(N_NODES + BM - 1) / BM, 256, 0, stream>>>(agg, wbf, bias, out);
}

// Round 6
// 200.675 us; speedup vs baseline: 6.1763x; 1.0787x over previous
//
#include <hip/hip_runtime.h>
#include <hip/hip_bf16.h>

#define N_NODES 50000
#define DIM 256
#define N_EDGES 320000
#define BM 32
#define LDA 264     // bf16 elems per LDS row: 256+8 pad -> 132 dwords ≡ 1 (mod 32): bank-conflict-free
#define SCAN_NB 196 // ceil(50000/256)
#define GEMM_NT ((N_NODES + BM - 1) / BM)  // 1563
#define GEMM_GRID 521                      // 521 * 3 == 1563 exactly

typedef __attribute__((ext_vector_type(8))) short short8;
typedef __attribute__((ext_vector_type(4))) float f32x4;
typedef __attribute__((ext_vector_type(4))) unsigned short ushort4v;

struct alignas(8) Pay { int idx; float nrm; };

static __device__ __forceinline__ unsigned short f2bf(float f) {
  unsigned int u = __float_as_uint(f);
  return (unsigned short)((u + 0x7FFFu + ((u >> 16) & 1u)) >> 16);  // RNE
}
static __device__ __forceinline__ float bf2f(unsigned short s) {
  return __uint_as_float(((unsigned int)s) << 16);
}

// Fused independent prep: [0,EB) emb->bf16, [EB,EB+64) W->bf16, rest: degree count.
template <int FULL>
__global__ __launch_bounds__(256) void k_misc(const float* __restrict__ emb,
                                              unsigned short* __restrict__ ebf,
                                              const float* __restrict__ W,
                                              unsigned short* __restrict__ wbf,
                                              const int* __restrict__ dst,
                                              int* __restrict__ deg) {
  const int EB = FULL ? 12500 : 0;
  int b = blockIdx.x;
  if (FULL && b < EB) {
    int i = b * 256 + threadIdx.x;
    const float4 v = ((const float4*)emb)[i];
    ushort4v r;
    r.x = f2bf(v.x); r.y = f2bf(v.y); r.z = f2bf(v.z); r.w = f2bf(v.w);
    *(ushort4v*)(ebf + (size_t)i * 4) = r;
  } else if (b < EB + 64) {
    int i = (b - EB) * 256 + threadIdx.x;
    const float4 v = ((const float4*)W)[i];
    ushort4v r;
    r.x = f2bf(v.x); r.y = f2bf(v.y); r.z = f2bf(v.z); r.w = f2bf(v.w);
    *(ushort4v*)(wbf + (size_t)i * 4) = r;
  } else {
    int e = (b - EB - 64) * 256 + threadIdx.x;
    if (e < N_EDGES) atomicAdd(&deg[dst[e]], 1);
  }
}

// ---- hierarchical exclusive scan of deg -> offs/cursor/dinv ----
__global__ __launch_bounds__(256) void k_scan1(const int* __restrict__ deg,
                                               int* __restrict__ bsum) {
  int i = blockIdx.x * 256 + threadIdx.x;
  int v = (i < N_NODES) ? deg[i] : 0;
#pragma unroll
  for (int off = 32; off; off >>= 1) v += __shfl_xor(v, off, 64);
  __shared__ int ws[4];
  if ((threadIdx.x & 63) == 0) ws[threadIdx.x >> 6] = v;
  __syncthreads();
  if (threadIdx.x == 0) bsum[blockIdx.x] = ws[0] + ws[1] + ws[2] + ws[3];
}

__global__ __launch_bounds__(256) void k_scan2(const int* __restrict__ bsum,
                                               int* __restrict__ bbase) {
  __shared__ int wsum[4], wb[4];
  int tid = threadIdx.x, lane = tid & 63, wv = tid >> 6;
  int v = (tid < SCAN_NB) ? bsum[tid] : 0;
  int x = v;
#pragma unroll
  for (int off = 1; off < 64; off <<= 1) {
    int y = __shfl_up(x, off, 64);
    if (lane >= off) x += y;
  }
  if (lane == 63) wsum[wv] = x;
  __syncthreads();
  if (tid == 0) { int s = 0; for (int k = 0; k < 4; ++k) { int t = wsum[k]; wb[k] = s; s += t; } }
  __syncthreads();
  if (tid < SCAN_NB) bbase[tid] = wb[wv] + (x - v);
}

__global__ __launch_bounds__(256) void k_scan3(const int* __restrict__ deg,
                                               const int* __restrict__ bbase,
                                               int* __restrict__ offs,
                                               int* __restrict__ cursor,
                                               float* __restrict__ dinv) {
  __shared__ int wsum[4], wb[4];
  int tid = threadIdx.x, lane = tid & 63, wv = tid >> 6;
  int i = blockIdx.x * 256 + tid;
  int v = (i < N_NODES) ? deg[i] : 0;
  int x = v;
#pragma unroll
  for (int off = 1; off < 64; off <<= 1) {
    int y = __shfl_up(x, off, 64);
    if (lane >= off) x += y;
  }
  if (lane == 63) wsum[wv] = x;
  __syncthreads();
  if (tid == 0) { int s = 0; for (int k = 0; k < 4; ++k) { int t = wsum[k]; wb[k] = s; s += t; } }
  __syncthreads();
  if (i < N_NODES) {
    int excl = bbase[blockIdx.x] + wb[wv] + (x - v);
    offs[i] = excl;
    cursor[i] = excl;
    dinv[i] = rsqrtf((float)(v + 1));  // +1 self-loop
  }
  if (blockIdx.x == 0 && tid == 0) offs[N_NODES] = N_EDGES;
}

// Bucket edges by dst: payload = {emb row of src, norm}.
__global__ __launch_bounds__(256) void k_scatter(const int* __restrict__ src,
                                                 const int* __restrict__ dst,
                                                 const int* __restrict__ nodes,
                                                 const float* __restrict__ dinv,
                                                 int* __restrict__ cursor,
                                                 Pay* __restrict__ pay) {
  int e = blockIdx.x * 256 + threadIdx.x;
  if (e >= N_EDGES) return;
  int s = src[e], d = dst[e];
  int pos = atomicAdd(&cursor[d], 1);
  Pay p;
  p.idx = nodes[s];
  p.nrm = dinv[s] * dinv[d];
  pay[pos] = p;
}

// One wave per dst node, 4-way MLP unroll; bf16 in (EMBBF) / fp32 in, bf16 agg out.
template <int EMBBF>
__global__ __launch_bounds__(256) void k_gather(const int* __restrict__ nodes,
                                                const float* __restrict__ dinv,
                                                const void* __restrict__ embv,
                                                const int* __restrict__ offs,
                                                const Pay* __restrict__ pay,
                                                unsigned short* __restrict__ agg) {
  int d = (blockIdx.x * 256 + threadIdx.x) >> 6;
  if (d >= N_NODES) return;
  const int lane = threadIdx.x & 63;
  const float dd = dinv[d];
  const int nr = nodes[d];
  const float sl = dd * dd;
  float4 acc;
  if (EMBBF) {
    const ushort4v s4 = ((const ushort4v*)((const unsigned short*)embv + (size_t)nr * DIM))[lane];
    acc = make_float4(bf2f(s4.x) * sl, bf2f(s4.y) * sl, bf2f(s4.z) * sl, bf2f(s4.w) * sl);
  } else {
    const float4 v = ((const float4*)((const float*)embv + (size_t)nr * DIM))[lane];
    acc = make_float4(v.x * sl, v.y * sl, v.z * sl, v.w * sl);
  }
  const int jb = offs[d], je = offs[d + 1];
  int e = jb;
  for (; e + 4 <= je; e += 4) {
    const Pay p0 = pay[e], p1 = pay[e + 1], p2 = pay[e + 2], p3 = pay[e + 3];
    if (EMBBF) {
      const unsigned short* eb = (const unsigned short*)embv;
      const ushort4v w0 = ((const ushort4v*)(eb + (size_t)p0.idx * DIM))[lane];
      const ushort4v w1 = ((const ushort4v*)(eb + (size_t)p1.idx * DIM))[lane];
      const ushort4v w2 = ((const ushort4v*)(eb + (size_t)p2.idx * DIM))[lane];
      const ushort4v w3 = ((const ushort4v*)(eb + (size_t)p3.idx * DIM))[lane];
      acc.x += bf2f(w0.x) * p0.nrm + bf2f(w1.x) * p1.nrm + bf2f(w2.x) * p2.nrm + bf2f(w3.x) * p3.nrm;
      acc.y += bf2f(w0.y) * p0.nrm + bf2f(w1.y) * p1.nrm + bf2f(w2.y) * p2.nrm + bf2f(w3.y) * p3.nrm;
      acc.z += bf2f(w0.z) * p0.nrm + bf2f(w1.z) * p1.nrm + bf2f(w2.z) * p2.nrm + bf2f(w3.z) * p3.nrm;
      acc.w += bf2f(w0.w) * p0.nrm + bf2f(w1.w) * p1.nrm + bf2f(w2.w) * p2.nrm + bf2f(w3.w) * p3.nrm;
    } else {
      const float* ef = (const float*)embv;
      const float4 w0 = ((const float4*)(ef + (size_t)p0.idx * DIM))[lane];
      const float4 w1 = ((const float4*)(ef + (size_t)p1.idx * DIM))[lane];
      const float4 w2 = ((const float4*)(ef + (size_t)p2.idx * DIM))[lane];
      const float4 w3 = ((const float4*)(ef + (size_t)p3.idx * DIM))[lane];
      acc.x += w0.x * p0.nrm + w1.x * p1.nrm + w2.x * p2.nrm + w3.x * p3.nrm;
      acc.y += w0.y * p0.nrm + w1.y * p1.nrm + w2.y * p2.nrm + w3.y * p3.nrm;
      acc.z += w0.z * p0.nrm + w1.z * p1.nrm + w2.z * p2.nrm + w3.z * p3.nrm;
      acc.w += w0.w * p0.nrm + w1.w * p1.nrm + w2.w * p2.nrm + w3.w * p3.nrm;
    }
  }
  for (; e < je; ++e) {
    const Pay p = pay[e];
    if (EMBBF) {
      const ushort4v w = ((const ushort4v*)((const unsigned short*)embv + (size_t)p.idx * DIM))[lane];
      acc.x += bf2f(w.x) * p.nrm; acc.y += bf2f(w.y) * p.nrm;
      acc.z += bf2f(w.z) * p.nrm; acc.w += bf2f(w.w) * p.nrm;
    } else {
      const float4 w = ((const float4*)((const float*)embv + (size_t)p.idx * DIM))[lane];
      acc.x += w.x * p.nrm; acc.y += w.y * p.nrm;
      acc.z += w.z * p.nrm; acc.w += w.w * p.nrm;
    }
  }
  ushort4v o;
  o.x = f2bf(acc.x); o.y = f2bf(acc.y); o.z = f2bf(acc.z); o.w = f2bf(acc.w);
  ((ushort4v*)(agg + (size_t)d * DIM))[lane] = o;
}

// out = relu(agg_bf16 @ W^T + b). B-stationary: W frags in registers (loaded once
// per block), grid-stride over 32-row tiles with double-buffered LDS A staging and
// issue-early register prefetch (T14). One __syncthreads per tile (double buffer:
// the buffer being overwritten was last read two iterations ago, behind 2 barriers).
// C/D: col=lane&15, row=(lane>>4)*4+reg [guide-verified m89/m91]
__global__ __launch_bounds__(256) void k_gemm(const unsigned short* __restrict__ agg,
                                              const unsigned short* __restrict__ wbf,
                                              const float* __restrict__ bias,
                                              float* __restrict__ out) {
  __shared__ unsigned short As[2][BM * LDA];
  const int tid = threadIdx.x;
  const int wv = tid >> 6, lane = tid & 63;
  const int l15 = lane & 15, kq = lane >> 4;
  const int cb = wv * 64;

  // B fragments for this wave's 64-col block: 32 x short8 (128 VGPR), loaded once.
  short8 bf[8][4];
#pragma unroll
  for (int ks = 0; ks < 8; ++ks)
#pragma unroll
    for (int f = 0; f < 4; ++f)
      bf[ks][f] = *(const short8*)(wbf + (size_t)(cb + f * 16 + l15) * 256 + ks * 32 + kq * 8);
  float bv[4];
#pragma unroll
  for (int f = 0; f < 4; ++f) bv[f] = bias[cb + f * 16 + l15];

  // A staging coords: 32 threads/row x 16B, 4 row-passes of 8.
  const int c = (tid & 31) * 8;
  const int rb = tid >> 5;

  // Prefetch first tile into registers.
  int t = blockIdx.x;
  short8 pre[4];
#pragma unroll
  for (int p = 0; p < 4; ++p) {
    const int grow = t * BM + rb + p * 8;
    short8 v = {};
    if (grow < N_NODES) v = *(const short8*)(agg + (size_t)grow * DIM + c);
    pre[p] = v;
  }

  int cur = 0;
  for (; t < GEMM_NT; t += gridDim.x) {
    // Write staged regs into LDS[cur].
#pragma unroll
    for (int p = 0; p < 4; ++p)
      *(short8*)&As[cur][(rb + p * 8) * LDA + c] = pre[p];
    __syncthreads();

    // Issue next tile's global loads early — latency hides under the MFMAs below.
    const int tn = t + gridDim.x;
    if (tn < GEMM_NT) {
#pragma unroll
      for (int p = 0; p < 4; ++p) {
        const int grow = tn * BM + rb + p * 8;
        short8 v = {};
        if (grow < N_NODES) v = *(const short8*)(agg + (size_t)grow * DIM + c);
        pre[p] = v;
      }
    }

    f32x4 acc[2][4] = {};
#pragma unroll
    for (int ks = 0; ks < 8; ++ks) {
      const int kb = ks * 32 + kq * 8;
      short8 a0 = *(const short8*)&As[cur][l15 * LDA + kb];
      short8 a1 = *(const short8*)&As[cur][(16 + l15) * LDA + kb];
#pragma unroll
      for (int f = 0; f < 4; ++f) {
        acc[0][f] = __builtin_amdgcn_mfma_f32_16x16x32_bf16(a0, bf[ks][f], acc[0][f], 0, 0, 0);
        acc[1][f] = __builtin_amdgcn_mfma_f32_16x16x32_bf16(a1, bf[ks][f], acc[1][f], 0, 0, 0);
      }
    }

    const int row0 = t * BM;
#pragma unroll
    for (int h = 0; h < 2; ++h) {
      int rbo = row0 + h * 16 + kq * 4;
#pragma unroll
      for (int f = 0; f < 4; ++f) {
        int col = cb + f * 16 + l15;
#pragma unroll
        for (int g = 0; g < 4; ++g) {
          int r = rbo + g;
          if (r < N_NODES) {
            float v = acc[h][f][g] + bv[f];
            __builtin_nontemporal_store(fmaxf(v, 0.f), &out[(size_t)r * DIM + col]);
          }
        }
      }
    }
    cur ^= 1;
  }
}

extern "C" void kernel_launch(void* const* d_in, const int* in_sizes, int n_in,
                              void* d_out, int out_size, void* d_ws, size_t ws_size,
                              hipStream_t stream) {
  const int* nodes = (const int*)d_in[0];
  const int* edges = (const int*)d_in[1];
  const float* emb = (const float*)d_in[2];
  const float* W = (const float*)d_in[3];
  const float* bias = (const float*)d_in[4];
  float* out = (float*)d_out;

  // Workspace layout (bytes):
  //   deg    @ 0        (200704)
  //   dinv   @ 200704   (200704)
  //   offs   @ 401408   (200704)
  //   cursor @ 602112   (200704)
  //   bsum   @ 802816   (1024)
  //   bbase  @ 803840   (1024)
  //   wbf    @ 804864   (131072)
  //   pay    @ 935936   (2560000)
  //   ebf    @ 3495936  (25600000)
  //   agg    @ 29095936 (25600000)  -> total 54695936
  int* deg = (int*)d_ws;
  float* dinv = (float*)((char*)d_ws + 200704);
  int* offs = (int*)((char*)d_ws + 401408);
  int* cursor = (int*)((char*)d_ws + 602112);
  int* bsum = (int*)((char*)d_ws + 802816);
  int* bbase = (int*)((char*)d_ws + 803840);
  unsigned short* wbf = (unsigned short*)((char*)d_ws + 804864);
  Pay* pay = (Pay*)((char*)d_ws + 935936);
  unsigned short* ebf = (unsigned short*)((char*)d_ws + 3495936);
  unsigned short* agg = (unsigned short*)((char*)d_ws + 29095936);
  const bool full = ws_size >= 54695936ull;
  if (!full) agg = (unsigned short*)((char*)d_ws + 3495936);  // reuse ebf slot

  const int* srcp = edges;             // edges[0]
  const int* dstp = edges + N_EDGES;   // edges[1]

  hipMemsetAsync(deg, 0, N_NODES * sizeof(int), stream);
  if (full)
    k_misc<1><<<12500 + 64 + 1250, 256, 0, stream>>>(emb, ebf, W, wbf, dstp, deg);
  else
    k_misc<0><<<64 + 1250, 256, 0, stream>>>(emb, ebf, W, wbf, dstp, deg);
  k_scan1<<<SCAN_NB, 256, 0, stream>>>(deg, bsum);
  k_scan2<<<1, 256, 0, stream>>>(bsum, bbase);
  k_scan3<<<SCAN_NB, 256, 0, stream>>>(deg, bbase, offs, cursor, dinv);
  k_scatter<<<(N_EDGES + 255) / 256, 256, 0, stream>>>(srcp, dstp, nodes, dinv, cursor, pay);
  if (full)
    k_gather<1><<<(N_NODES * 64 + 255) / 256, 256, 0, stream>>>(nodes, dinv, ebf, offs, pay, agg);
  else
    k_gather<0><<<(N_NODES * 64 + 255) / 256, 256, 0, stream>>>(nodes, dinv, emb, offs, pay, agg);
  k_gemm<<<GEMM_GRID, 256, 0, stream>>>(agg, wbf, bias, out);
}

// Round 7
// 196.889 us; speedup vs baseline: 6.2951x; 1.0192x over previous
//
#include <hip/hip_runtime.h>
#include <hip/hip_bf16.h>

#define N_NODES 50000
#define DIM 256
#define N_EDGES 320000
#define BM 32
#define LDA 264     // bf16 elems per LDS row: 256+8 pad -> 132 dwords ≡ 1 (mod 32): bank-conflict-free
#define SCAN_NB 196 // ceil(50000/256)
#define GEMM_NT ((N_NODES + BM - 1) / BM)  // 1563
#define GEMM_GRID 521                      // 521 * 3 == 1563 exactly

typedef __attribute__((ext_vector_type(8))) short short8;
typedef __attribute__((ext_vector_type(4))) float f32x4;
typedef __attribute__((ext_vector_type(4))) unsigned short ushort4v;

struct alignas(8) Pay { int idx; float nrm; };

static __device__ __forceinline__ unsigned short f2bf(float f) {
  unsigned int u = __float_as_uint(f);
  return (unsigned short)((u + 0x7FFFu + ((u >> 16) & 1u)) >> 16);  // RNE
}
static __device__ __forceinline__ float bf2f(unsigned short s) {
  return __uint_as_float(((unsigned int)s) << 16);
}

// Fused independent prep: [0,EB) emb->bf16, [EB,EB+64) W->bf16, rest: degree count.
template <int FULL>
__global__ __launch_bounds__(256) void k_misc(const float* __restrict__ emb,
                                              unsigned short* __restrict__ ebf,
                                              const float* __restrict__ W,
                                              unsigned short* __restrict__ wbf,
                                              const int* __restrict__ dst,
                                              int* __restrict__ deg) {
  const int EB = FULL ? 12500 : 0;
  int b = blockIdx.x;
  if (FULL && b < EB) {
    int i = b * 256 + threadIdx.x;
    const float4 v = ((const float4*)emb)[i];
    ushort4v r;
    r.x = f2bf(v.x); r.y = f2bf(v.y); r.z = f2bf(v.z); r.w = f2bf(v.w);
    *(ushort4v*)(ebf + (size_t)i * 4) = r;
  } else if (b < EB + 64) {
    int i = (b - EB) * 256 + threadIdx.x;
    const float4 v = ((const float4*)W)[i];
    ushort4v r;
    r.x = f2bf(v.x); r.y = f2bf(v.y); r.z = f2bf(v.z); r.w = f2bf(v.w);
    *(ushort4v*)(wbf + (size_t)i * 4) = r;
  } else {
    int e = (b - EB - 64) * 256 + threadIdx.x;
    if (e < N_EDGES) atomicAdd(&deg[dst[e]], 1);
  }
}

// ---- scan pass 1: per-block sums of deg ----
__global__ __launch_bounds__(256) void k_scan1(const int* __restrict__ deg,
                                               int* __restrict__ bsum) {
  int i = blockIdx.x * 256 + threadIdx.x;
  int v = (i < N_NODES) ? deg[i] : 0;
#pragma unroll
  for (int off = 32; off; off >>= 1) v += __shfl_xor(v, off, 64);
  __shared__ int ws[4];
  if ((threadIdx.x & 63) == 0) ws[threadIdx.x >> 6] = v;
  __syncthreads();
  if (threadIdx.x == 0) bsum[blockIdx.x] = ws[0] + ws[1] + ws[2] + ws[3];
}

// ---- scan passes 2+3 fused: each block derives its own base from bsum, then
// does the intra-block exclusive scan -> offs/cursor/dinv ----
__global__ __launch_bounds__(256) void k_scan23(const int* __restrict__ deg,
                                                const int* __restrict__ bsum,
                                                int* __restrict__ offs,
                                                int* __restrict__ cursor,
                                                float* __restrict__ dinv) {
  __shared__ int wsum[4], wb[4], bbase_sh;
  const int tid = threadIdx.x, lane = tid & 63, wv = tid >> 6;

  // bbase = sum of bsum[j] for j < blockIdx.x   (SCAN_NB=196 <= 256 threads)
  int contrib = (tid < blockIdx.x && tid < SCAN_NB) ? bsum[tid] : 0;
#pragma unroll
  for (int off = 32; off; off >>= 1) contrib += __shfl_xor(contrib, off, 64);
  if (lane == 0) wsum[wv] = contrib;
  __syncthreads();
  if (tid == 0) bbase_sh = wsum[0] + wsum[1] + wsum[2] + wsum[3];
  __syncthreads();

  const int i = blockIdx.x * 256 + tid;
  const int v = (i < N_NODES) ? deg[i] : 0;
  int x = v;
#pragma unroll
  for (int off = 1; off < 64; off <<= 1) {
    int y = __shfl_up(x, off, 64);
    if (lane >= off) x += y;
  }
  if (lane == 63) wsum[wv] = x;
  __syncthreads();
  if (tid == 0) { int s = 0; for (int k = 0; k < 4; ++k) { int t = wsum[k]; wb[k] = s; s += t; } }
  __syncthreads();
  if (i < N_NODES) {
    int excl = bbase_sh + wb[wv] + (x - v);
    offs[i] = excl;
    cursor[i] = excl;
    dinv[i] = rsqrtf((float)(v + 1));  // +1 self-loop
  }
  if (blockIdx.x == 0 && tid == 0) offs[N_NODES] = N_EDGES;
}

// Bucket edges by dst: payload = {emb row of src, norm}.
__global__ __launch_bounds__(256) void k_scatter(const int* __restrict__ src,
                                                 const int* __restrict__ dst,
                                                 const int* __restrict__ nodes,
                                                 const float* __restrict__ dinv,
                                                 int* __restrict__ cursor,
                                                 Pay* __restrict__ pay) {
  int e = blockIdx.x * 256 + threadIdx.x;
  if (e >= N_EDGES) return;
  int s = src[e], d = dst[e];
  int pos = atomicAdd(&cursor[d], 1);
  Pay p;
  p.idx = nodes[s];
  p.nrm = dinv[s] * dinv[d];
  pay[pos] = p;
}

// One wave per dst node, 4-way MLP unroll; bf16 in (EMBBF) / fp32 in, bf16 agg out.
template <int EMBBF>
__global__ __launch_bounds__(256) void k_gather(const int* __restrict__ nodes,
                                                const float* __restrict__ dinv,
                                                const void* __restrict__ embv,
                                                const int* __restrict__ offs,
                                                const Pay* __restrict__ pay,
                                                unsigned short* __restrict__ agg) {
  int d = (blockIdx.x * 256 + threadIdx.x) >> 6;
  if (d >= N_NODES) return;
  const int lane = threadIdx.x & 63;
  const float dd = dinv[d];
  const int nr = nodes[d];
  const float sl = dd * dd;
  float4 acc;
  if (EMBBF) {
    const ushort4v s4 = ((const ushort4v*)((const unsigned short*)embv + (size_t)nr * DIM))[lane];
    acc = make_float4(bf2f(s4.x) * sl, bf2f(s4.y) * sl, bf2f(s4.z) * sl, bf2f(s4.w) * sl);
  } else {
    const float4 v = ((const float4*)((const float*)embv + (size_t)nr * DIM))[lane];
    acc = make_float4(v.x * sl, v.y * sl, v.z * sl, v.w * sl);
  }
  const int jb = offs[d], je = offs[d + 1];
  int e = jb;
  for (; e + 4 <= je; e += 4) {
    const Pay p0 = pay[e], p1 = pay[e + 1], p2 = pay[e + 2], p3 = pay[e + 3];
    if (EMBBF) {
      const unsigned short* eb = (const unsigned short*)embv;
      const ushort4v w0 = ((const ushort4v*)(eb + (size_t)p0.idx * DIM))[lane];
      const ushort4v w1 = ((const ushort4v*)(eb + (size_t)p1.idx * DIM))[lane];
      const ushort4v w2 = ((const ushort4v*)(eb + (size_t)p2.idx * DIM))[lane];
      const ushort4v w3 = ((const ushort4v*)(eb + (size_t)p3.idx * DIM))[lane];
      acc.x += bf2f(w0.x) * p0.nrm + bf2f(w1.x) * p1.nrm + bf2f(w2.x) * p2.nrm + bf2f(w3.x) * p3.nrm;
      acc.y += bf2f(w0.y) * p0.nrm + bf2f(w1.y) * p1.nrm + bf2f(w2.y) * p2.nrm + bf2f(w3.y) * p3.nrm;
      acc.z += bf2f(w0.z) * p0.nrm + bf2f(w1.z) * p1.nrm + bf2f(w2.z) * p2.nrm + bf2f(w3.z) * p3.nrm;
      acc.w += bf2f(w0.w) * p0.nrm + bf2f(w1.w) * p1.nrm + bf2f(w2.w) * p2.nrm + bf2f(w3.w) * p3.nrm;
    } else {
      const float* ef = (const float*)embv;
      const float4 w0 = ((const float4*)(ef + (size_t)p0.idx * DIM))[lane];
      const float4 w1 = ((const float4*)(ef + (size_t)p1.idx * DIM))[lane];
      const float4 w2 = ((const float4*)(ef + (size_t)p2.idx * DIM))[lane];
      const float4 w3 = ((const float4*)(ef + (size_t)p3.idx * DIM))[lane];
      acc.x += w0.x * p0.nrm + w1.x * p1.nrm + w2.x * p2.nrm + w3.x * p3.nrm;
      acc.y += w0.y * p0.nrm + w1.y * p1.nrm + w2.y * p2.nrm + w3.y * p3.nrm;
      acc.z += w0.z * p0.nrm + w1.z * p1.nrm + w2.z * p2.nrm + w3.z * p3.nrm;
      acc.w += w0.w * p0.nrm + w1.w * p1.nrm + w2.w * p2.nrm + w3.w * p3.nrm;
    }
  }
  for (; e < je; ++e) {
    const Pay p = pay[e];
    if (EMBBF) {
      const ushort4v w = ((const ushort4v*)((const unsigned short*)embv + (size_t)p.idx * DIM))[lane];
      acc.x += bf2f(w.x) * p.nrm; acc.y += bf2f(w.y) * p.nrm;
      acc.z += bf2f(w.z) * p.nrm; acc.w += bf2f(w.w) * p.nrm;
    } else {
      const float4 w = ((const float4*)((const float*)embv + (size_t)p.idx * DIM))[lane];
      acc.x += w.x * p.nrm; acc.y += w.y * p.nrm;
      acc.z += w.z * p.nrm; acc.w += w.w * p.nrm;
    }
  }
  ushort4v o;
  o.x = f2bf(acc.x); o.y = f2bf(acc.y); o.z = f2bf(acc.z); o.w = f2bf(acc.w);
  ((ushort4v*)(agg + (size_t)d * DIM))[lane] = o;
}

// out = relu(agg_bf16 @ W^T + b). B-stationary, 8 waves x 32-col blocks (512 thr):
// B-frags bf[8][2] = 64 VGPR -> <=128 total, 4 waves/SIMD via __launch_bounds__(512,4).
// Grid-stride over 32-row tiles, double-buffered LDS A, issue-early prefetch (T14),
// one __syncthreads per tile. C/D: col=lane&15, row=(lane>>4)*4+reg [m89/m91].
__global__ __launch_bounds__(512, 4) void k_gemm(const unsigned short* __restrict__ agg,
                                                 const unsigned short* __restrict__ wbf,
                                                 const float* __restrict__ bias,
                                                 float* __restrict__ out) {
  __shared__ unsigned short As[2][BM * LDA];
  const int tid = threadIdx.x;
  const int wv = tid >> 6, lane = tid & 63;
  const int l15 = lane & 15, kq = lane >> 4;
  const int cb = wv * 32;

  // B fragments for this wave's 32-col block: 16 x short8 (64 VGPR), loaded once.
  short8 bf[8][2];
#pragma unroll
  for (int ks = 0; ks < 8; ++ks)
#pragma unroll
    for (int f = 0; f < 2; ++f)
      bf[ks][f] = *(const short8*)(wbf + (size_t)(cb + f * 16 + l15) * 256 + ks * 32 + kq * 8);
  float bv[2];
#pragma unroll
  for (int f = 0; f < 2; ++f) bv[f] = bias[cb + f * 16 + l15];

  // A staging coords: 32 lanes/row x 16B; 512 threads cover 16 rows/pass, 2 passes.
  const int c = (tid & 31) * 8;
  const int rb = tid >> 5;  // 0..15

  // Prefetch first tile into registers.
  int t = blockIdx.x;
  short8 pre[2];
#pragma unroll
  for (int p = 0; p < 2; ++p) {
    const int grow = t * BM + rb + p * 16;
    short8 v = {};
    if (grow < N_NODES) v = *(const short8*)(agg + (size_t)grow * DIM + c);
    pre[p] = v;
  }

  int cur = 0;
  for (; t < GEMM_NT; t += gridDim.x) {
#pragma unroll
    for (int p = 0; p < 2; ++p)
      *(short8*)&As[cur][(rb + p * 16) * LDA + c] = pre[p];
    __syncthreads();

    // Issue next tile's global loads early — latency hides under the MFMAs below.
    const int tn = t + gridDim.x;
    if (tn < GEMM_NT) {
#pragma unroll
      for (int p = 0; p < 2; ++p) {
        const int grow = tn * BM + rb + p * 16;
        short8 v = {};
        if (grow < N_NODES) v = *(const short8*)(agg + (size_t)grow * DIM + c);
        pre[p] = v;
      }
    }

    f32x4 acc[2][2] = {};
#pragma unroll
    for (int ks = 0; ks < 8; ++ks) {
      const int kb = ks * 32 + kq * 8;
      short8 a0 = *(const short8*)&As[cur][l15 * LDA + kb];
      short8 a1 = *(const short8*)&As[cur][(16 + l15) * LDA + kb];
#pragma unroll
      for (int f = 0; f < 2; ++f) {
        acc[0][f] = __builtin_amdgcn_mfma_f32_16x16x32_bf16(a0, bf[ks][f], acc[0][f], 0, 0, 0);
        acc[1][f] = __builtin_amdgcn_mfma_f32_16x16x32_bf16(a1, bf[ks][f], acc[1][f], 0, 0, 0);
      }
    }

    const int row0 = t * BM;
#pragma unroll
    for (int h = 0; h < 2; ++h) {
      int rbo = row0 + h * 16 + kq * 4;
#pragma unroll
      for (int f = 0; f < 2; ++f) {
        int col = cb + f * 16 + l15;
#pragma unroll
        for (int g = 0; g < 4; ++g) {
          int r = rbo + g;
          if (r < N_NODES) {
            float v = acc[h][f][g] + bv[f];
            __builtin_nontemporal_store(fmaxf(v, 0.f), &out[(size_t)r * DIM + col]);
          }
        }
      }
    }
    cur ^= 1;
  }
}

extern "C" void kernel_launch(void* const* d_in, const int* in_sizes, int n_in,
                              void* d_out, int out_size, void* d_ws, size_t ws_size,
                              hipStream_t stream) {
  const int* nodes = (const int*)d_in[0];
  const int* edges = (const int*)d_in[1];
  const float* emb = (const float*)d_in[2];
  const float* W = (const float*)d_in[3];
  const float* bias = (const float*)d_in[4];
  float* out = (float*)d_out;

  // Workspace layout (bytes):
  //   deg    @ 0        (200704)
  //   dinv   @ 200704   (200704)
  //   offs   @ 401408   (200704)
  //   cursor @ 602112   (200704)
  //   bsum   @ 802816   (1024)
  //   (gap)  @ 803840
  //   wbf    @ 804864   (131072)
  //   pay    @ 935936   (2560000)
  //   ebf    @ 3495936  (25600000)
  //   agg    @ 29095936 (25600000)  -> total 54695936
  int* deg = (int*)d_ws;
  float* dinv = (float*)((char*)d_ws + 200704);
  int* offs = (int*)((char*)d_ws + 401408);
  int* cursor = (int*)((char*)d_ws + 602112);
  int* bsum = (int*)((char*)d_ws + 802816);
  unsigned short* wbf = (unsigned short*)((char*)d_ws + 804864);
  Pay* pay = (Pay*)((char*)d_ws + 935936);
  unsigned short* ebf = (unsigned short*)((char*)d_ws + 3495936);
  unsigned short* agg = (unsigned short*)((char*)d_ws + 29095936);
  const bool full = ws_size >= 54695936ull;
  if (!full) agg = (unsigned short*)((char*)d_ws + 3495936);  // reuse ebf slot

  const int* srcp = edges;             // edges[0]
  const int* dstp = edges + N_EDGES;   // edges[1]

  hipMemsetAsync(deg, 0, N_NODES * sizeof(int), stream);
  if (full)
    k_misc<1><<<12500 + 64 + 1250, 256, 0, stream>>>(emb, ebf, W, wbf, dstp, deg);
  else
    k_misc<0><<<64 + 1250, 256, 0, stream>>>(emb, ebf, W, wbf, dstp, deg);
  k_scan1<<<SCAN_NB, 256, 0, stream>>>(deg, bsum);
  k_scan23<<<SCAN_NB, 256, 0, stream>>>(deg, bsum, offs, cursor, dinv);
  k_scatter<<<(N_EDGES + 255) / 256, 256, 0, stream>>>(srcp, dstp, nodes, dinv, cursor, pay);
  if (full)
    k_gather<1><<<(N_NODES * 64 + 255) / 256, 256, 0, stream>>>(nodes, dinv, ebf, offs, pay, agg);
  else
    k_gather<0><<<(N_NODES * 64 + 255) / 256, 256, 0, stream>>>(nodes, dinv, emb, offs, pay, agg);
  k_gemm<<<GEMM_GRID, 512, 0, stream>>>(agg, wbf, bias, out);
}